// Round 9
// baseline (35.923 us; speedup 1.0000x reference)
//
#include <hip/hip_runtime.h>
#include <math.h>

#define WHVI_D 2048

typedef int   v2i __attribute__((ext_vector_type(2)));
typedef float v4f __attribute__((ext_vector_type(4)));

// ---------------------------------------------------------------------------
// In-register butterfly over the 32-reg dimension, xor-mask M (i bits 0,1,8,9,10).
// ---------------------------------------------------------------------------
template <int M>
__device__ __forceinline__ void bfly_reg(float (&v)[32]) {
#pragma unroll
    for (int r = 0; r < 32; ++r) {
        if (!(r & M)) {
            float a = v[r], c = v[r ^ M];
            v[r]     = a + c;
            v[r ^ M] = a - c;
        }
    }
}

// ---------------------------------------------------------------------------
// Lane-xor butterfly via DPP (VALU pipe): p = v[lane^k]; v = sgn*v + p.
// CTRL: 0xB1 = quad_perm [1,0,3,2] (xor1), 0x4E = [2,3,0,1] (xor2),
//       0x128 = row_ror:8 (xor8 within 16-lane rows).
// ---------------------------------------------------------------------------
template <int CTRL>
__device__ __forceinline__ void bfly_dpp(float (&v)[32], float sgn) {
#pragma unroll
    for (int r = 0; r < 32; ++r) {
        int p = __builtin_amdgcn_mov_dpp(__float_as_int(v[r]), CTRL, 0xF, 0xF, false);
        v[r] = fmaf(sgn, v[r], __int_as_float(p));
    }
}

// Lane-xor-4 via ds_swizzle BitMode: offset = (4<<10)|(0<<5)|31 = 0x101F.
__device__ __forceinline__ void bfly_swz4(float (&v)[32], float sgn) {
#pragma unroll
    for (int r = 0; r < 32; ++r) {
        int p = __builtin_amdgcn_ds_swizzle(__float_as_int(v[r]), 0x101F);
        v[r] = fmaf(sgn, v[r], __int_as_float(p));
    }
}

// ---------------------------------------------------------------------------
// Lane-xor 16 / 32 via v_permlane16/32_swap_b32 pair trick (2 regs at a time):
// swap(a,b); s=a'+b', d=a'-b'; swap(s,d) -> butterfly results for both regs.
// ---------------------------------------------------------------------------
template <bool IS32>
__device__ __forceinline__ void bfly_permlane(float (&v)[32]) {
#pragma unroll
    for (int r = 0; r < 32; r += 2) {
        int a = __float_as_int(v[r]), b = __float_as_int(v[r + 1]);
        v2i t;
        if constexpr (IS32) t = __builtin_amdgcn_permlane32_swap(a, b, false, false);
        else                t = __builtin_amdgcn_permlane16_swap(a, b, false, false);
        float s = __int_as_float(t.x) + __int_as_float(t.y);
        float d = __int_as_float(t.x) - __int_as_float(t.y);
        v2i wv;
        if constexpr (IS32) wv = __builtin_amdgcn_permlane32_swap(__float_as_int(s), __float_as_int(d), false, false);
        else                wv = __builtin_amdgcn_permlane16_swap(__float_as_int(s), __float_as_int(d), false, false);
        v[r]     = __int_as_float(wv.x);
        v[r + 1] = __int_as_float(wv.y);
    }
}

// Full 2048-point FWHT, layout P: reg r=j*4+c, lane L -> i = j*256 + L*4 + c.
__device__ __forceinline__ void fwht(float (&v)[32], float sg1, float sg2,
                                     float sg4, float sg8) {
    bfly_reg<1>(v); bfly_reg<2>(v); bfly_reg<4>(v); bfly_reg<8>(v); bfly_reg<16>(v);
    bfly_dpp<0xB1>(v, sg1);    // i bit 2
    bfly_dpp<0x4E>(v, sg2);    // i bit 3
    bfly_swz4(v, sg4);         // i bit 4
    bfly_dpp<0x128>(v, sg8);   // i bit 5
    bfly_permlane<false>(v);   // i bit 6
    bfly_permlane<true>(v);    // i bit 7
}

__device__ __forceinline__ float4 ld4(const float* p) {
    return *reinterpret_cast<const float4*>(p);
}

// ---------------------------------------------------------------------------
// 256-thread blocks, 4 waves; each wave owns 2 consecutive rows, software-
// pipelined so every FWHT burst runs with 8 HBM loads in flight (row B's
// loads are issued the moment row A's xv registers are consumed). Broadcasts
// (s1, s2, u) staged into 24 KB LDS once per block -> per-row VMEM is exactly
// 8 loads + 8 nontemporal stores; broadcast reads ride the DS pipe. No
// launch-bounds arg2 (avoids the 64-VGPR clamp seen in rounds 3/7); live
// state v[32]+xv[8] fits ~100 VGPR -> 16 waves/CU, grid = 4 blocks/CU exactly.
// ---------------------------------------------------------------------------
__global__ __launch_bounds__(256) void whvi_main_kernel(
    const float* __restrict__ x,
    const float* __restrict__ s1,
    const float* __restrict__ s2,
    const float* __restrict__ g_mu,
    const float* __restrict__ g_rho,
    const float* __restrict__ eps,
    float* __restrict__ out)
{
    __shared__ __align__(16) float sU[WHVI_D];
    __shared__ __align__(16) float sS1[WHVI_D];
    __shared__ __align__(16) float sS2[WHVI_D];

    const int  tid  = threadIdx.x;
    const int  wid  = tid >> 6;
    const int  lane = tid & 63;
    const int  lo   = lane * 4;
    const long rowA = ((long)blockIdx.x * 4 + wid) * 2;
    const long rowB = rowA + 1;

    // ---- issue row-A x loads first (longest latency path) ----
    const float* xrA = x + rowA * WHVI_D;
    float4 xv[8];
#pragma unroll
    for (int j = 0; j < 8; ++j)
        xv[j] = ld4(xrA + j * 256 + lo);

    // ---- cooperative staging of s1, s2, u into LDS (hides under x latency) ----
#pragma unroll
    for (int k = 0; k < 2; ++k) {
        const int o = (k * 256 + tid) * 4;
        *reinterpret_cast<float4*>(&sS2[o]) = ld4(s2 + o);
        *reinterpret_cast<float4*>(&sS1[o]) = ld4(s1 + o);
        const float4 rv = ld4(g_rho + o);
        const float4 ev = ld4(eps + o);
        const float4 mv = ld4(g_mu + o);
        float4 u;
        float sp;
        sp  = fmaxf(rv.x, 0.0f) + __logf(1.0f + __expf(-fabsf(rv.x)));
        u.x = fmaf(sqrtf(sp), ev.x, mv.x) * (1.0f / 2048.0f);
        sp  = fmaxf(rv.y, 0.0f) + __logf(1.0f + __expf(-fabsf(rv.y)));
        u.y = fmaf(sqrtf(sp), ev.y, mv.y) * (1.0f / 2048.0f);
        sp  = fmaxf(rv.z, 0.0f) + __logf(1.0f + __expf(-fabsf(rv.z)));
        u.z = fmaf(sqrtf(sp), ev.z, mv.z) * (1.0f / 2048.0f);
        sp  = fmaxf(rv.w, 0.0f) + __logf(1.0f + __expf(-fabsf(rv.w)));
        u.w = fmaf(sqrtf(sp), ev.w, mv.w) * (1.0f / 2048.0f);
        *reinterpret_cast<float4*>(&sU[o]) = u;
    }
    __syncthreads();

    const float sg1 = (lane & 1) ? -1.0f : 1.0f;
    const float sg2 = (lane & 2) ? -1.0f : 1.0f;
    const float sg4 = (lane & 4) ? -1.0f : 1.0f;
    const float sg8 = (lane & 8) ? -1.0f : 1.0f;

    float v[32];

    // ==================== row A ====================
#pragma unroll
    for (int j = 0; j < 8; ++j) {
        const float4 sv = ld4(&sS2[j * 256 + lo]);
        v[j * 4 + 0] = xv[j].x * sv.x;
        v[j * 4 + 1] = xv[j].y * sv.y;
        v[j * 4 + 2] = xv[j].z * sv.z;
        v[j * 4 + 3] = xv[j].w * sv.w;
    }

    // prefetch row B: 8 HBM loads stay in flight across row A's compute burst
    const float* xrB = x + rowB * WHVI_D;
#pragma unroll
    for (int j = 0; j < 8; ++j)
        xv[j] = ld4(xrB + j * 256 + lo);

    fwht(v, sg1, sg2, sg4, sg8);
#pragma unroll
    for (int j = 0; j < 8; ++j) {
        const float4 uv = ld4(&sU[j * 256 + lo]);
        v[j * 4 + 0] *= uv.x;
        v[j * 4 + 1] *= uv.y;
        v[j * 4 + 2] *= uv.z;
        v[j * 4 + 3] *= uv.w;
    }
    fwht(v, sg1, sg2, sg4, sg8);

    {
        float* orow = out + rowA * WHVI_D;
#pragma unroll
        for (int j = 0; j < 8; ++j) {
            const float4 sv = ld4(&sS1[j * 256 + lo]);
            v4f ov;
            ov.x = v[j * 4 + 0] * sv.x;
            ov.y = v[j * 4 + 1] * sv.y;
            ov.z = v[j * 4 + 2] * sv.z;
            ov.w = v[j * 4 + 3] * sv.w;
            __builtin_nontemporal_store(ov, reinterpret_cast<v4f*>(orow + j * 256 + lo));
        }
    }

    // ==================== row B ====================
#pragma unroll
    for (int j = 0; j < 8; ++j) {
        const float4 sv = ld4(&sS2[j * 256 + lo]);
        v[j * 4 + 0] = xv[j].x * sv.x;
        v[j * 4 + 1] = xv[j].y * sv.y;
        v[j * 4 + 2] = xv[j].z * sv.z;
        v[j * 4 + 3] = xv[j].w * sv.w;
    }

    fwht(v, sg1, sg2, sg4, sg8);
#pragma unroll
    for (int j = 0; j < 8; ++j) {
        const float4 uv = ld4(&sU[j * 256 + lo]);
        v[j * 4 + 0] *= uv.x;
        v[j * 4 + 1] *= uv.y;
        v[j * 4 + 2] *= uv.z;
        v[j * 4 + 3] *= uv.w;
    }
    fwht(v, sg1, sg2, sg4, sg8);

    {
        float* orow = out + rowB * WHVI_D;
#pragma unroll
        for (int j = 0; j < 8; ++j) {
            const float4 sv = ld4(&sS1[j * 256 + lo]);
            v4f ov;
            ov.x = v[j * 4 + 0] * sv.x;
            ov.y = v[j * 4 + 1] * sv.y;
            ov.z = v[j * 4 + 2] * sv.z;
            ov.w = v[j * 4 + 3] * sv.w;
            __builtin_nontemporal_store(ov, reinterpret_cast<v4f*>(orow + j * 256 + lo));
        }
    }
}

extern "C" void kernel_launch(void* const* d_in, const int* in_sizes, int n_in,
                              void* d_out, int out_size, void* d_ws, size_t ws_size,
                              hipStream_t stream)
{
    const float* x     = (const float*)d_in[0];
    const float* s1    = (const float*)d_in[1];
    const float* s2    = (const float*)d_in[2];
    const float* g_mu  = (const float*)d_in[3];
    const float* g_rho = (const float*)d_in[4];
    const float* eps   = (const float*)d_in[5];
    // d_in[6] = H unused: fast Walsh-Hadamard transform instead.

    float* outp = (float*)d_out;
    const int rows = out_size / WHVI_D;              // 8192
    const int blocks = rows / 8;                     // 4 waves * 2 rows per block
    whvi_main_kernel<<<blocks, 256, 0, stream>>>(x, s1, s2, g_mu, g_rho, eps, outp);
}

// Round 10
// 28.052 us; speedup vs baseline: 1.2806x; 1.2806x over previous
//
#include <hip/hip_runtime.h>
#include <math.h>

#define WHVI_D 2048

typedef int   v2i __attribute__((ext_vector_type(2)));
typedef float v4f __attribute__((ext_vector_type(4)));

// ---------------------------------------------------------------------------
// In-register butterfly over the 32-reg dimension, xor-mask M (i bits 0,1,8,9,10).
// ---------------------------------------------------------------------------
template <int M>
__device__ __forceinline__ void bfly_reg(float (&v)[32]) {
#pragma unroll
    for (int r = 0; r < 32; ++r) {
        if (!(r & M)) {
            float a = v[r], c = v[r ^ M];
            v[r]     = a + c;
            v[r ^ M] = a - c;
        }
    }
}

// ---------------------------------------------------------------------------
// Lane-xor butterfly via DPP (VALU pipe): p = v[lane^k]; v = sgn*v + p.
// CTRL: 0xB1 = quad_perm [1,0,3,2] (xor1), 0x4E = [2,3,0,1] (xor2),
//       0x128 = row_ror:8 (xor8 within 16-lane rows).
// ---------------------------------------------------------------------------
template <int CTRL>
__device__ __forceinline__ void bfly_dpp(float (&v)[32], float sgn) {
#pragma unroll
    for (int r = 0; r < 32; ++r) {
        int p = __builtin_amdgcn_mov_dpp(__float_as_int(v[r]), CTRL, 0xF, 0xF, false);
        v[r] = fmaf(sgn, v[r], __int_as_float(p));
    }
}

// Lane-xor-4 via ds_swizzle BitMode: offset = (4<<10)|(0<<5)|31 = 0x101F.
__device__ __forceinline__ void bfly_swz4(float (&v)[32], float sgn) {
#pragma unroll
    for (int r = 0; r < 32; ++r) {
        int p = __builtin_amdgcn_ds_swizzle(__float_as_int(v[r]), 0x101F);
        v[r] = fmaf(sgn, v[r], __int_as_float(p));
    }
}

// ---------------------------------------------------------------------------
// Lane-xor 16 / 32 via v_permlane16/32_swap_b32 pair trick (2 regs at a time):
// swap(a,b); s=a'+b', d=a'-b'; swap(s,d) -> butterfly results for both regs.
// ---------------------------------------------------------------------------
template <bool IS32>
__device__ __forceinline__ void bfly_permlane(float (&v)[32]) {
#pragma unroll
    for (int r = 0; r < 32; r += 2) {
        int a = __float_as_int(v[r]), b = __float_as_int(v[r + 1]);
        v2i t;
        if constexpr (IS32) t = __builtin_amdgcn_permlane32_swap(a, b, false, false);
        else                t = __builtin_amdgcn_permlane16_swap(a, b, false, false);
        float s = __int_as_float(t.x) + __int_as_float(t.y);
        float d = __int_as_float(t.x) - __int_as_float(t.y);
        v2i wv;
        if constexpr (IS32) wv = __builtin_amdgcn_permlane32_swap(__float_as_int(s), __float_as_int(d), false, false);
        else                wv = __builtin_amdgcn_permlane16_swap(__float_as_int(s), __float_as_int(d), false, false);
        v[r]     = __int_as_float(wv.x);
        v[r + 1] = __int_as_float(wv.y);
    }
}

// Full 2048-point FWHT, layout P: reg r=j*4+c, lane L -> i = j*256 + L*4 + c.
__device__ __forceinline__ void fwht(float (&v)[32], float sg1, float sg2,
                                     float sg4, float sg8) {
    bfly_reg<1>(v); bfly_reg<2>(v); bfly_reg<4>(v); bfly_reg<8>(v); bfly_reg<16>(v);
    bfly_dpp<0xB1>(v, sg1);    // i bit 2
    bfly_dpp<0x4E>(v, sg2);    // i bit 3
    bfly_swz4(v, sg4);         // i bit 4
    bfly_dpp<0x128>(v, sg8);   // i bit 5
    bfly_permlane<false>(v);   // i bit 6
    bfly_permlane<true>(v);    // i bit 7
}

__device__ __forceinline__ float4 ld4(const float* p) {
    return *reinterpret_cast<const float4*>(p);
}

// ---------------------------------------------------------------------------
// 1 row per wave, 2048 blocks, max TLP. u and s2 staged in 16 KB LDS once per
// block (10 blocks/CU LDS-wise); s1 read from global in the epilogue (L1-hot
// 8 KB, latency overlaps the store drain). x loaded in two batches of 4
// float4 consumed immediately -> peak live regs ~= v[32] + 16 + temps ~ 64,
// giving ~8 waves/SIMD = 32 waves/CU of mutually desynchronized waves.
// ---------------------------------------------------------------------------
__global__ __launch_bounds__(256) void whvi_main_kernel(
    const float* __restrict__ x,
    const float* __restrict__ s1,
    const float* __restrict__ s2,
    const float* __restrict__ g_mu,
    const float* __restrict__ g_rho,
    const float* __restrict__ eps,
    float* __restrict__ out)
{
    __shared__ __align__(16) float sU[WHVI_D];
    __shared__ __align__(16) float sS2[WHVI_D];

    const int  tid  = threadIdx.x;
    const int  wid  = tid >> 6;
    const int  lane = tid & 63;
    const int  lo   = lane * 4;
    const long row  = (long)blockIdx.x * 4 + wid;

    const float* xr = x + row * WHVI_D;

    // ---- batch 0: first 4 x-loads (longest latency path) ----
    float4 xa = ld4(xr + 0 * 256 + lo);
    float4 xb = ld4(xr + 1 * 256 + lo);
    float4 xc = ld4(xr + 2 * 256 + lo);
    float4 xd = ld4(xr + 3 * 256 + lo);

    // ---- cooperative staging of s2, u into LDS (hides under x latency) ----
#pragma unroll
    for (int k = 0; k < 2; ++k) {
        const int o = (k * 256 + tid) * 4;
        *reinterpret_cast<float4*>(&sS2[o]) = ld4(s2 + o);
        const float4 rv = ld4(g_rho + o);
        const float4 ev = ld4(eps + o);
        const float4 mv = ld4(g_mu + o);
        float4 u;
        float sp;
        sp  = fmaxf(rv.x, 0.0f) + __logf(1.0f + __expf(-fabsf(rv.x)));
        u.x = fmaf(sqrtf(sp), ev.x, mv.x) * (1.0f / 2048.0f);
        sp  = fmaxf(rv.y, 0.0f) + __logf(1.0f + __expf(-fabsf(rv.y)));
        u.y = fmaf(sqrtf(sp), ev.y, mv.y) * (1.0f / 2048.0f);
        sp  = fmaxf(rv.z, 0.0f) + __logf(1.0f + __expf(-fabsf(rv.z)));
        u.z = fmaf(sqrtf(sp), ev.z, mv.z) * (1.0f / 2048.0f);
        sp  = fmaxf(rv.w, 0.0f) + __logf(1.0f + __expf(-fabsf(rv.w)));
        u.w = fmaf(sqrtf(sp), ev.w, mv.w) * (1.0f / 2048.0f);
        *reinterpret_cast<float4*>(&sU[o]) = u;
    }
    __syncthreads();

    const float sg1 = (lane & 1) ? -1.0f : 1.0f;
    const float sg2 = (lane & 2) ? -1.0f : 1.0f;
    const float sg4 = (lane & 4) ? -1.0f : 1.0f;
    const float sg8 = (lane & 8) ? -1.0f : 1.0f;

    float v[32];

    // ---- batch 1 issued, then batch 0 consumed (frees its regs) ----
    float4 xe = ld4(xr + 4 * 256 + lo);
    float4 xf = ld4(xr + 5 * 256 + lo);
    float4 xg = ld4(xr + 6 * 256 + lo);
    float4 xh = ld4(xr + 7 * 256 + lo);

    {
        float4 sv;
        sv = ld4(&sS2[0 * 256 + lo]);
        v[ 0] = xa.x * sv.x; v[ 1] = xa.y * sv.y; v[ 2] = xa.z * sv.z; v[ 3] = xa.w * sv.w;
        sv = ld4(&sS2[1 * 256 + lo]);
        v[ 4] = xb.x * sv.x; v[ 5] = xb.y * sv.y; v[ 6] = xb.z * sv.z; v[ 7] = xb.w * sv.w;
        sv = ld4(&sS2[2 * 256 + lo]);
        v[ 8] = xc.x * sv.x; v[ 9] = xc.y * sv.y; v[10] = xc.z * sv.z; v[11] = xc.w * sv.w;
        sv = ld4(&sS2[3 * 256 + lo]);
        v[12] = xd.x * sv.x; v[13] = xd.y * sv.y; v[14] = xd.z * sv.z; v[15] = xd.w * sv.w;
        sv = ld4(&sS2[4 * 256 + lo]);
        v[16] = xe.x * sv.x; v[17] = xe.y * sv.y; v[18] = xe.z * sv.z; v[19] = xe.w * sv.w;
        sv = ld4(&sS2[5 * 256 + lo]);
        v[20] = xf.x * sv.x; v[21] = xf.y * sv.y; v[22] = xf.z * sv.z; v[23] = xf.w * sv.w;
        sv = ld4(&sS2[6 * 256 + lo]);
        v[24] = xg.x * sv.x; v[25] = xg.y * sv.y; v[26] = xg.z * sv.z; v[27] = xg.w * sv.w;
        sv = ld4(&sS2[7 * 256 + lo]);
        v[28] = xh.x * sv.x; v[29] = xh.y * sv.y; v[30] = xh.z * sv.z; v[31] = xh.w * sv.w;
    }

    fwht(v, sg1, sg2, sg4, sg8);

#pragma unroll
    for (int j = 0; j < 8; ++j) {
        const float4 uv = ld4(&sU[j * 256 + lo]);
        v[j * 4 + 0] *= uv.x;
        v[j * 4 + 1] *= uv.y;
        v[j * 4 + 2] *= uv.z;
        v[j * 4 + 3] *= uv.w;
    }

    fwht(v, sg1, sg2, sg4, sg8);

    // ---- epilogue: s1 from global (L1-hot), nontemporal store ----
    float* orow = out + row * WHVI_D;
#pragma unroll
    for (int j = 0; j < 8; ++j) {
        const float4 sv = ld4(s1 + j * 256 + lo);
        v4f ov;
        ov.x = v[j * 4 + 0] * sv.x;
        ov.y = v[j * 4 + 1] * sv.y;
        ov.z = v[j * 4 + 2] * sv.z;
        ov.w = v[j * 4 + 3] * sv.w;
        __builtin_nontemporal_store(ov, reinterpret_cast<v4f*>(orow + j * 256 + lo));
    }
}

extern "C" void kernel_launch(void* const* d_in, const int* in_sizes, int n_in,
                              void* d_out, int out_size, void* d_ws, size_t ws_size,
                              hipStream_t stream)
{
    const float* x     = (const float*)d_in[0];
    const float* s1    = (const float*)d_in[1];
    const float* s2    = (const float*)d_in[2];
    const float* g_mu  = (const float*)d_in[3];
    const float* g_rho = (const float*)d_in[4];
    const float* eps   = (const float*)d_in[5];
    // d_in[6] = H unused: fast Walsh-Hadamard transform instead.

    float* outp = (float*)d_out;
    const int rows = out_size / WHVI_D;              // 8192
    whvi_main_kernel<<<rows / 4, 256, 0, stream>>>(x, s1, s2, g_mu, g_rho, eps, outp);
}